// Round 1
// baseline (118.918 us; speedup 1.0000x reference)
//
#include <hip/hip_runtime.h>

// Problem constants: B=16, C=512, H=W=14 (HW=196), D=8000.
#define B_DIM 16
#define C_DIM 512
#define HW_DIM 196
#define D_DIM 8000
#define KP 224                      // K padded to 7*32 for MFMA 16x16x32
#define NROW (B_DIM * C_DIM)        // 8192 rows in xp

typedef __attribute__((ext_vector_type(8))) short short8;   // 8 bf16 frag
typedef __attribute__((ext_vector_type(4))) float float4v;  // 4 f32 acc

// ---------------------------------------------------------------------------
// Kernel 1 (prep), 1024 blocks x 256:
//  every block:  (A) scan ONE row of S1|S2 for its (hash,sign) with chunked
//                    early-exit (halves the old 2-row serial chain),
//                (B) convert 8 rows of x fp32 -> bf16, pad K 196 -> 224,
//                (C) zero a 128-float slice of out (gram_hist accumulates
//                    into out atomically now; out may be poisoned).
// 4 blocks/CU -> scan latency chains overlap with conversion BW.
// NOTE (R8 lesson): no device-scope fences / inter-block sync anywhere.
// NOTE (R7/R10 lesson): grid covers all 256 CUs with >=2 waves/SIMD.
// ---------------------------------------------------------------------------
__global__ __launch_bounds__(256) void prep(
    const float* __restrict__ x, const float* __restrict__ S1,
    const float* __restrict__ S2,
    int* __restrict__ h, float* __restrict__ s,
    unsigned short* __restrict__ xp, float* __restrict__ out) {
    const int bid = blockIdx.x;          // 0..1023
    const int tid = threadIdx.x;

    // ---- Phase A: one sketch row per block ------------------------------
    {
        const int row   = bid & (C_DIM - 1);
        const int which = bid >> 9;      // 0 -> S1, 1 -> S2
        const float4* rowp =
            (const float4*)((which ? S2 : S1) + (size_t)row * D_DIM);
        int*   hp = h + which * C_DIM;
        float* sp = s + which * C_DIM;
        __shared__ int found;
        if (tid == 0) found = 0;
        __syncthreads();
        for (int c = 0; c < 8; ++c) {    // 8 chunks of 256 float4
            int j4 = c * 256 + tid;
            if (j4 < D_DIM / 4) {
                float4 v = rowp[j4];
                if (v.x != 0.f) { hp[row] = 4 * j4 + 0; sp[row] = v.x; found = 1; }
                if (v.y != 0.f) { hp[row] = 4 * j4 + 1; sp[row] = v.y; found = 1; }
                if (v.z != 0.f) { hp[row] = 4 * j4 + 2; sp[row] = v.z; found = 1; }
                if (v.w != 0.f) { hp[row] = 4 * j4 + 3; sp[row] = v.w; found = 1; }
            }
            __syncthreads();
            if (found) break;            // uniform after barrier
        }
    }

    // ---- Phase B: convert 8 rows of x (fp32 -> bf16 RNE, pad to KP) -----
    #pragma unroll
    for (int l = 0; l < 7; ++l) {        // 7*256 = 1792 = 8*224
        int idx = l * 256 + tid;
        int r   = idx / KP;
        int kk  = idx - r * KP;
        int row = bid * 8 + r;
        float v = (kk < HW_DIM) ? x[(size_t)row * HW_DIM + kk] : 0.0f;
        unsigned int u = __float_as_uint(v);   // RNE fp32 -> bf16
        u = (u + 0x7FFFu + ((u >> 16) & 1u)) >> 16;
        xp[(size_t)row * KP + kk] = (unsigned short)u;
    }

    // ---- Phase C: zero out[16*8000] (1000 blocks x 32 float4 = 128000) --
    if (bid < 1000 && tid < 32)
        ((float4*)out)[bid * 32 + tid] = (float4){0.f, 0.f, 0.f, 0.f};
}

// ---------------------------------------------------------------------------
// Kernel 2: barrier-free MFMA Gram, 128x128 block tile, 512 threads =
// 8 waves (4 i x 2 j wave-grid of the proven 32x64 wave tile). All 256 CUs
// covered, 2 waves/SIMD. Epilogue now flushes the LDS histogram DIRECTLY
// into out[b,:] with device-scope atomicAdd (out zeroed by prep) — kills the
// 8.2 MB part-write + 8.2 MB re-read + third dispatch of the old scheme.
// LDS = 32 KB histogram only.
// ---------------------------------------------------------------------------
__global__ __launch_bounds__(512) void gram_hist(
    const unsigned short* __restrict__ xp,   // [B*C, KP] bf16 bits
    const int* __restrict__ h, const float* __restrict__ s,
    float* __restrict__ out) {               // [B, D] accumulated atomically
    const int jb = blockIdx.x;               // 0..3
    const int ib = blockIdx.y;               // 0..3
    const int b  = blockIdx.z;               // 0..15
    const int tid = threadIdx.x;

    __shared__ __align__(16) float hist[D_DIM];
    #pragma unroll
    for (int l4 = 0; l4 < 4; ++l4) {
        int i4 = l4 * 512 + tid;
        if (i4 < D_DIM / 4)
            ((float4*)hist)[i4] = (float4){0.f, 0.f, 0.f, 0.f};
    }
    __syncthreads();

    const int w  = tid >> 6;    // wave 0..7: iw = w&3, jw = w>>2
    const int l  = tid & 63;
    const int rA = l & 15;      // fragment row within 16x16 tile
    const int g  = l >> 4;      // k-group: 8 contiguous k at g*8

    const int i0 = ib * 128 + (w & 3) * 32;
    const int j0 = jb * 128 + (w >> 2) * 64;

    const unsigned short* base = xp + (size_t)b * C_DIM * KP;
    const unsigned short* pA[2];
    const unsigned short* pB[4];
    #pragma unroll
    for (int mt = 0; mt < 2; ++mt)
        pA[mt] = base + (size_t)(i0 + mt * 16 + rA) * KP + g * 8;
    #pragma unroll
    for (int nt = 0; nt < 4; ++nt)
        pB[nt] = base + (size_t)(j0 + nt * 16 + rA) * KP + g * 8;

    float4v acc[2][4];
    #pragma unroll
    for (int mt = 0; mt < 2; ++mt)
        #pragma unroll
        for (int nt = 0; nt < 4; ++nt)
            acc[mt][nt] = (float4v){0.0f, 0.0f, 0.0f, 0.0f};

    short8 fa[2], fb[4];
    #pragma unroll
    for (int mt = 0; mt < 2; ++mt) fa[mt] = *(const short8*)pA[mt];
    #pragma unroll
    for (int nt = 0; nt < 4; ++nt) fb[nt] = *(const short8*)pB[nt];

    // 7 K-steps of 32; register double-buffered prefetch; zero barriers.
    #pragma unroll
    for (int step = 1; step <= 7; ++step) {
        short8 na[2], nb[4];
        if (step < 7) {
            #pragma unroll
            for (int mt = 0; mt < 2; ++mt) na[mt] = *(const short8*)(pA[mt] + step * 32);
            #pragma unroll
            for (int nt = 0; nt < 4; ++nt) nb[nt] = *(const short8*)(pB[nt] + step * 32);
        }
        #pragma unroll
        for (int mt = 0; mt < 2; ++mt)
            #pragma unroll
            for (int nt = 0; nt < 4; ++nt)
                acc[mt][nt] = __builtin_amdgcn_mfma_f32_16x16x32_bf16(
                    fa[mt], fb[nt], acc[mt][nt], 0, 0, 0);
        if (step < 7) {
            #pragma unroll
            for (int mt = 0; mt < 2; ++mt) fa[mt] = na[mt];
            #pragma unroll
            for (int nt = 0; nt < 4; ++nt) fb[nt] = nb[nt];
        }
    }

    // Scatter: C/D layout col = lane&15, row = (lane>>4)*4 + reg (verified).
    int hr[2][4]; float sr[2][4]; int hc[4]; float sc[4];
    #pragma unroll
    for (int mt = 0; mt < 2; ++mt)
        #pragma unroll
        for (int rg = 0; rg < 4; ++rg) {
            int c1 = i0 + mt * 16 + (l >> 4) * 4 + rg;
            hr[mt][rg] = h[c1]; sr[mt][rg] = s[c1];
        }
    #pragma unroll
    for (int nt = 0; nt < 4; ++nt) {
        int c2 = j0 + nt * 16 + (l & 15);
        hc[nt] = h[C_DIM + c2]; sc[nt] = s[C_DIM + c2];
    }
    #pragma unroll
    for (int mt = 0; mt < 2; ++mt)
        #pragma unroll
        for (int nt = 0; nt < 4; ++nt)
            #pragma unroll
            for (int rg = 0; rg < 4; ++rg) {
                int bin = hr[mt][rg] + hc[nt];
                if (bin >= D_DIM) bin -= D_DIM;
                atomicAdd(&hist[bin], sr[mt][rg] * sc[nt] * acc[mt][nt][rg]);
            }
    __syncthreads();

    // Flush: coalesced device-scope atomicAdd into out[b,:]. ~13% of bins
    // are exactly zero (e^-2 vacancy of 16K updates into 8K bins) — skip.
    float* ob = out + (size_t)b * D_DIM;
    for (int i = tid; i < D_DIM; i += 512) {
        float v = hist[i];
        if (v != 0.0f) atomicAdd(&ob[i], v);
    }
}

extern "C" void kernel_launch(void* const* d_in, const int* in_sizes, int n_in,
                              void* d_out, int out_size, void* d_ws, size_t ws_size,
                              hipStream_t stream) {
    const float* x  = (const float*)d_in[0];  // [16, 512, 14, 14] fp32
    const float* S1 = (const float*)d_in[1];  // [512, 8000] fp32
    const float* S2 = (const float*)d_in[2];  // [512, 8000] fp32
    float* out = (float*)d_out;               // [16, 8000] fp32

    // ws: h[1024] int | s[1024] f32 | xp[8192*224] bf16 (3.7 MB)
    int*            h  = (int*)d_ws;
    float*          s  = (float*)(h + 2 * C_DIM);
    unsigned short* xp = (unsigned short*)(s + 2 * C_DIM);

    prep<<<1024, 256, 0, stream>>>(x, S1, S2, h, s, xp, out);

    dim3 grid(4, 4, B_DIM);                   // 256 blocks, 128x128 tiles
    gram_hist<<<grid, 512, 0, stream>>>(xp, h, s, out);
}

// Round 2
// 114.297 us; speedup vs baseline: 1.0404x; 1.0404x over previous
//
#include <hip/hip_runtime.h>

// Problem constants: B=16, C=512, H=W=14 (HW=196), D=8000.
#define B_DIM 16
#define C_DIM 512
#define HW_DIM 196
#define D_DIM 8000
#define KP 224                      // K padded to 7*32 for MFMA 16x16x32
#define NROW (B_DIM * C_DIM)        // 8192 rows in xp

typedef __attribute__((ext_vector_type(8))) short short8;   // 8 bf16 frag
typedef __attribute__((ext_vector_type(4))) float float4v;  // 4 f32 acc

// ---------------------------------------------------------------------------
// Kernel 1 (prep), 1024 blocks x 256:
//  every block:  (A) branchless full-row scan of ONE row of S1|S2: all 8
//                    float4 loads issued unconditionally (no early-exit
//                    barrier chain — R1 post-mortem: the serial chunk loop
//                    was an un-hideable ~4.5-deep load->barrier chain).
//                    The single lane holding the row's one nonzero stores
//                    (h,s) directly. No flag, no barriers, no race.
//                (B) convert 8 rows of x fp32 -> bf16, pad K 196 -> 224.
// 4 blocks/CU; everything pipelines as pure bandwidth.
// NOTE (R8 lesson): no device-scope fences / inter-block sync anywhere.
// NOTE (R7/R10 lesson): grid covers all 256 CUs with >=2 waves/SIMD.
// ---------------------------------------------------------------------------
__global__ __launch_bounds__(256) void prep(
    const float* __restrict__ x, const float* __restrict__ S1,
    const float* __restrict__ S2,
    int* __restrict__ h, float* __restrict__ s,
    unsigned short* __restrict__ xp) {
    const int bid = blockIdx.x;          // 0..1023
    const int tid = threadIdx.x;

    // ---- Phase A: one sketch row per block, branchless ------------------
    {
        const int row   = bid & (C_DIM - 1);
        const int which = bid >> 9;      // 0 -> S1, 1 -> S2
        const float4* rowp =
            (const float4*)((which ? S2 : S1) + (size_t)row * D_DIM);
        int   myh = -1;
        float mys = 0.0f;
        #pragma unroll
        for (int c = 0; c < 8; ++c) {    // 8 independent chunks, all in flight
            int j4 = c * 256 + tid;
            if (j4 < D_DIM / 4) {
                float4 v = rowp[j4];
                if (v.x != 0.f) { myh = 4 * j4 + 0; mys = v.x; }
                if (v.y != 0.f) { myh = 4 * j4 + 1; mys = v.y; }
                if (v.z != 0.f) { myh = 4 * j4 + 2; mys = v.z; }
                if (v.w != 0.f) { myh = 4 * j4 + 3; mys = v.w; }
            }
        }
        if (myh >= 0) {                  // exactly one lane in the block
            h[which * C_DIM + row] = myh;
            s[which * C_DIM + row] = mys;
        }
    }

    // ---- Phase B: convert 8 rows of x (fp32 -> bf16 RNE, pad to KP) -----
    #pragma unroll
    for (int l = 0; l < 7; ++l) {        // 7*256 = 1792 = 8*224
        int idx = l * 256 + tid;
        int r   = idx / KP;
        int kk  = idx - r * KP;
        int row = bid * 8 + r;
        float v = (kk < HW_DIM) ? x[(size_t)row * HW_DIM + kk] : 0.0f;
        unsigned int u = __float_as_uint(v);   // RNE fp32 -> bf16
        u = (u + 0x7FFFu + ((u >> 16) & 1u)) >> 16;
        xp[(size_t)row * KP + kk] = (unsigned short)u;
    }
}

// ---------------------------------------------------------------------------
// Kernel 2: barrier-free MFMA Gram, 128x128 block tile, 512 threads =
// 8 waves (4 i x 2 j wave-grid of the proven 32x64 wave tile). All 256 CUs
// covered, 2 waves/SIMD. Flush = plain coalesced float4 stores to this
// block's private partial slice (R1 post-mortem: device-scope atomicAdd
// flush into shared out[b,:] from 16 blocks/b across XCDs regressed +2.6us;
// disjoint plain stores + separate reduce is faster).
// LDS = 32 KB histogram only.
// ---------------------------------------------------------------------------
__global__ __launch_bounds__(512) void gram_hist(
    const unsigned short* __restrict__ xp,   // [B*C, KP] bf16 bits
    const int* __restrict__ h, const float* __restrict__ s,
    float* __restrict__ part) {              // [256, D] partials
    const int jb = blockIdx.x;               // 0..3
    const int ib = blockIdx.y;               // 0..3
    const int b  = blockIdx.z;               // 0..15
    const int tid = threadIdx.x;

    __shared__ __align__(16) float hist[D_DIM];
    #pragma unroll
    for (int l4 = 0; l4 < 4; ++l4) {
        int i4 = l4 * 512 + tid;
        if (i4 < D_DIM / 4)
            ((float4*)hist)[i4] = (float4){0.f, 0.f, 0.f, 0.f};
    }
    __syncthreads();

    const int w  = tid >> 6;    // wave 0..7: iw = w&3, jw = w>>2
    const int l  = tid & 63;
    const int rA = l & 15;      // fragment row within 16x16 tile
    const int g  = l >> 4;      // k-group: 8 contiguous k at g*8

    const int i0 = ib * 128 + (w & 3) * 32;
    const int j0 = jb * 128 + (w >> 2) * 64;

    const unsigned short* base = xp + (size_t)b * C_DIM * KP;
    const unsigned short* pA[2];
    const unsigned short* pB[4];
    #pragma unroll
    for (int mt = 0; mt < 2; ++mt)
        pA[mt] = base + (size_t)(i0 + mt * 16 + rA) * KP + g * 8;
    #pragma unroll
    for (int nt = 0; nt < 4; ++nt)
        pB[nt] = base + (size_t)(j0 + nt * 16 + rA) * KP + g * 8;

    float4v acc[2][4];
    #pragma unroll
    for (int mt = 0; mt < 2; ++mt)
        #pragma unroll
        for (int nt = 0; nt < 4; ++nt)
            acc[mt][nt] = (float4v){0.0f, 0.0f, 0.0f, 0.0f};

    short8 fa[2], fb[4];
    #pragma unroll
    for (int mt = 0; mt < 2; ++mt) fa[mt] = *(const short8*)pA[mt];
    #pragma unroll
    for (int nt = 0; nt < 4; ++nt) fb[nt] = *(const short8*)pB[nt];

    // 7 K-steps of 32; register double-buffered prefetch; zero barriers.
    #pragma unroll
    for (int step = 1; step <= 7; ++step) {
        short8 na[2], nb[4];
        if (step < 7) {
            #pragma unroll
            for (int mt = 0; mt < 2; ++mt) na[mt] = *(const short8*)(pA[mt] + step * 32);
            #pragma unroll
            for (int nt = 0; nt < 4; ++nt) nb[nt] = *(const short8*)(pB[nt] + step * 32);
        }
        #pragma unroll
        for (int mt = 0; mt < 2; ++mt)
            #pragma unroll
            for (int nt = 0; nt < 4; ++nt)
                acc[mt][nt] = __builtin_amdgcn_mfma_f32_16x16x32_bf16(
                    fa[mt], fb[nt], acc[mt][nt], 0, 0, 0);
        if (step < 7) {
            #pragma unroll
            for (int mt = 0; mt < 2; ++mt) fa[mt] = na[mt];
            #pragma unroll
            for (int nt = 0; nt < 4; ++nt) fb[nt] = nb[nt];
        }
    }

    // Scatter: C/D layout col = lane&15, row = (lane>>4)*4 + reg (verified).
    int hr[2][4]; float sr[2][4]; int hc[4]; float sc[4];
    #pragma unroll
    for (int mt = 0; mt < 2; ++mt)
        #pragma unroll
        for (int rg = 0; rg < 4; ++rg) {
            int c1 = i0 + mt * 16 + (l >> 4) * 4 + rg;
            hr[mt][rg] = h[c1]; sr[mt][rg] = s[c1];
        }
    #pragma unroll
    for (int nt = 0; nt < 4; ++nt) {
        int c2 = j0 + nt * 16 + (l & 15);
        hc[nt] = h[C_DIM + c2]; sc[nt] = s[C_DIM + c2];
    }
    #pragma unroll
    for (int mt = 0; mt < 2; ++mt)
        #pragma unroll
        for (int nt = 0; nt < 4; ++nt)
            #pragma unroll
            for (int rg = 0; rg < 4; ++rg) {
                int bin = hr[mt][rg] + hc[nt];
                if (bin >= D_DIM) bin -= D_DIM;
                atomicAdd(&hist[bin], sr[mt][rg] * sc[nt] * acc[mt][nt][rg]);
            }
    __syncthreads();

    // Flush: plain coalesced float4 stores to this block's partial slice.
    const int slot = b * 16 + ib * 4 + jb;
    float* pb = part + (size_t)slot * D_DIM;
    #pragma unroll
    for (int l4 = 0; l4 < 4; ++l4) {
        int i4 = l4 * 512 + tid;
        if (i4 < D_DIM / 4)
            ((float4*)pb)[i4] = ((const float4*)hist)[i4];
    }
}

// ---------------------------------------------------------------------------
// Kernel 3: reduce the 16 partials of each batch -> out[b, d]. float4 loads,
// plain stores; fully overwrites out (no memset needed).
// ---------------------------------------------------------------------------
__global__ __launch_bounds__(256) void reduce_part(
    const float* __restrict__ part, float* __restrict__ out) {
    int i4 = blockIdx.x * 256 + threadIdx.x;     // over B*D/4 = 32000
    if (i4 >= B_DIM * D_DIM / 4) return;
    int b = i4 / (D_DIM / 4);
    int d = i4 - b * (D_DIM / 4);
    const float4* p = (const float4*)(part + (size_t)b * 16 * D_DIM) + d;
    float4 v = {0.f, 0.f, 0.f, 0.f};
    #pragma unroll
    for (int t = 0; t < 16; ++t) {
        float4 q = p[(size_t)t * (D_DIM / 4)];
        v.x += q.x; v.y += q.y; v.z += q.z; v.w += q.w;
    }
    ((float4*)out)[i4] = v;
}

extern "C" void kernel_launch(void* const* d_in, const int* in_sizes, int n_in,
                              void* d_out, int out_size, void* d_ws, size_t ws_size,
                              hipStream_t stream) {
    const float* x  = (const float*)d_in[0];  // [16, 512, 14, 14] fp32
    const float* S1 = (const float*)d_in[1];  // [512, 8000] fp32
    const float* S2 = (const float*)d_in[2];  // [512, 8000] fp32
    float* out = (float*)d_out;               // [16, 8000] fp32

    // ws: h[1024] int | s[1024] f32 | xp[8192*224] bf16 (3.7 MB)
    //   | part[256*8000] f32 (8.2 MB)
    int*            h    = (int*)d_ws;
    float*          s    = (float*)(h + 2 * C_DIM);
    unsigned short* xp   = (unsigned short*)(s + 2 * C_DIM);
    float*          part = (float*)(xp + (size_t)NROW * KP);

    prep<<<1024, 256, 0, stream>>>(x, S1, S2, h, s, xp);

    dim3 grid(4, 4, B_DIM);                   // 256 blocks, 128x128 tiles
    gram_hist<<<grid, 512, 0, stream>>>(xp, h, s, part);

    reduce_part<<<(B_DIM * D_DIM / 4 + 255) / 256, 256, 0, stream>>>(part, out);
}

// Round 3
// 112.649 us; speedup vs baseline: 1.0556x; 1.0146x over previous
//
#include <hip/hip_runtime.h>

// Problem constants: B=16, C=512, H=W=14 (HW=196), D=8000.
#define B_DIM 16
#define C_DIM 512
#define HW_DIM 196
#define D_DIM 8000
#define KP 224                      // K padded to 7*32 for MFMA 16x16x32
#define NROW (B_DIM * C_DIM)        // 8192 rows in xp

typedef __attribute__((ext_vector_type(8))) short short8;   // 8 bf16 frag
typedef __attribute__((ext_vector_type(4))) float float4v;  // 4 f32 acc

// ---------------------------------------------------------------------------
// Kernel 1 (prep), 1024 blocks x 256, software-pipelined for ILP:
//   1) ISSUE all 8 float4 loads of this block's S1|S2 row into registers
//      (addresses clamped, results predicated -> no divergence, no barriers).
//   2) Phase B runs entirely under that latency: convert 8 rows of x
//      fp32 -> bf16 RNE, PACKED (float2 load -> one u32 store of 2 bf16).
//   3) Resolve the A-registers; the single lane holding the row's one
//      nonzero stores (h,s). Exactly one lane matches -> no race.
// R1 post-mortem: early-exit chunk loop was an un-hideable serial
// load->barrier chain; R2 made it branchless; R3 hides it under Phase B.
// NOTE (R8 lesson): no device-scope fences / inter-block sync anywhere.
// ---------------------------------------------------------------------------
__global__ __launch_bounds__(256) void prep(
    const float* __restrict__ x, const float* __restrict__ S1,
    const float* __restrict__ S2,
    int* __restrict__ h, float* __restrict__ s,
    unsigned short* __restrict__ xp) {
    const int bid = blockIdx.x;          // 0..1023
    const int tid = threadIdx.x;

    // ---- 1) issue sketch-row loads (8 x float4, all in flight) ----------
    const int row   = bid & (C_DIM - 1);
    const int which = bid >> 9;          // 0 -> S1, 1 -> S2
    const float4* rowp =
        (const float4*)((which ? S2 : S1) + (size_t)row * D_DIM);
    float4 va[8];
    #pragma unroll
    for (int c = 0; c < 8; ++c) {
        int j4 = c * 256 + tid;
        if (j4 > D_DIM / 4 - 1) j4 = D_DIM / 4 - 1;   // clamp, predicate later
        va[c] = rowp[j4];
    }

    // ---- 2) Phase B: 8 rows of x fp32 -> bf16, packed 2-at-a-time -------
    // 8 rows * 112 u32 = 896 items; 4 iters of 256 threads.
    unsigned int* xw = (unsigned int*)xp;
    #pragma unroll
    for (int l = 0; l < 4; ++l) {
        int idx = l * 256 + tid;                     // 0..1023
        if (idx < 896) {
            int r   = idx / 112;
            int k2  = idx - r * 112;                 // u32 column, kk = 2*k2
            int row8 = bid * 8 + r;
            float v0 = 0.f, v1 = 0.f;
            if (k2 < 98) {                           // kk,kk+1 <= 195
                float2 p = *(const float2*)(x + (size_t)row8 * HW_DIM + 2 * k2);
                v0 = p.x; v1 = p.y;
            }
            unsigned int u0 = __float_as_uint(v0);   // RNE fp32 -> bf16
            u0 = (u0 + 0x7FFFu + ((u0 >> 16) & 1u)) >> 16;
            unsigned int u1 = __float_as_uint(v1);
            u1 = (u1 + 0x7FFFu + ((u1 >> 16) & 1u)) >> 16;
            xw[(size_t)row8 * (KP / 2) + k2] = (u1 << 16) | u0;
        }
    }

    // ---- 3) resolve sketch scan -----------------------------------------
    int   myh = -1;
    float mys = 0.0f;
    #pragma unroll
    for (int c = 0; c < 8; ++c) {
        int j4 = c * 256 + tid;
        if (j4 < D_DIM / 4) {
            float4 v = va[c];
            if (v.x != 0.f) { myh = 4 * j4 + 0; mys = v.x; }
            if (v.y != 0.f) { myh = 4 * j4 + 1; mys = v.y; }
            if (v.z != 0.f) { myh = 4 * j4 + 2; mys = v.z; }
            if (v.w != 0.f) { myh = 4 * j4 + 3; mys = v.w; }
        }
    }
    if (myh >= 0) {                      // exactly one lane in the block
        h[which * C_DIM + row] = myh;
        s[which * C_DIM + row] = mys;
    }
}

// ---------------------------------------------------------------------------
// Kernel 2: barrier-free MFMA Gram, 128x128 block tile, 512 threads =
// 8 waves (4 i x 2 j wave-grid of the proven 32x64 wave tile). All 256 CUs
// covered, 2 waves/SIMD. Flush = plain coalesced float4 stores to this
// block's private partial slice (R1 post-mortem: device-scope atomicAdd
// flush into shared out[b,:] from 16 blocks/b across XCDs regressed +2.6us;
// disjoint plain stores + separate reduce is faster).
// LDS = 32 KB histogram only.  (Unchanged from R2 — proven.)
// ---------------------------------------------------------------------------
__global__ __launch_bounds__(512) void gram_hist(
    const unsigned short* __restrict__ xp,   // [B*C, KP] bf16 bits
    const int* __restrict__ h, const float* __restrict__ s,
    float* __restrict__ part) {              // [256, D] partials
    const int jb = blockIdx.x;               // 0..3
    const int ib = blockIdx.y;               // 0..3
    const int b  = blockIdx.z;               // 0..15
    const int tid = threadIdx.x;

    __shared__ __align__(16) float hist[D_DIM];
    #pragma unroll
    for (int l4 = 0; l4 < 4; ++l4) {
        int i4 = l4 * 512 + tid;
        if (i4 < D_DIM / 4)
            ((float4*)hist)[i4] = (float4){0.f, 0.f, 0.f, 0.f};
    }
    __syncthreads();

    const int w  = tid >> 6;    // wave 0..7: iw = w&3, jw = w>>2
    const int l  = tid & 63;
    const int rA = l & 15;      // fragment row within 16x16 tile
    const int g  = l >> 4;      // k-group: 8 contiguous k at g*8

    const int i0 = ib * 128 + (w & 3) * 32;
    const int j0 = jb * 128 + (w >> 2) * 64;

    const unsigned short* base = xp + (size_t)b * C_DIM * KP;
    const unsigned short* pA[2];
    const unsigned short* pB[4];
    #pragma unroll
    for (int mt = 0; mt < 2; ++mt)
        pA[mt] = base + (size_t)(i0 + mt * 16 + rA) * KP + g * 8;
    #pragma unroll
    for (int nt = 0; nt < 4; ++nt)
        pB[nt] = base + (size_t)(j0 + nt * 16 + rA) * KP + g * 8;

    float4v acc[2][4];
    #pragma unroll
    for (int mt = 0; mt < 2; ++mt)
        #pragma unroll
        for (int nt = 0; nt < 4; ++nt)
            acc[mt][nt] = (float4v){0.0f, 0.0f, 0.0f, 0.0f};

    short8 fa[2], fb[4];
    #pragma unroll
    for (int mt = 0; mt < 2; ++mt) fa[mt] = *(const short8*)pA[mt];
    #pragma unroll
    for (int nt = 0; nt < 4; ++nt) fb[nt] = *(const short8*)pB[nt];

    // 7 K-steps of 32; register double-buffered prefetch; zero barriers.
    #pragma unroll
    for (int step = 1; step <= 7; ++step) {
        short8 na[2], nb[4];
        if (step < 7) {
            #pragma unroll
            for (int mt = 0; mt < 2; ++mt) na[mt] = *(const short8*)(pA[mt] + step * 32);
            #pragma unroll
            for (int nt = 0; nt < 4; ++nt) nb[nt] = *(const short8*)(pB[nt] + step * 32);
        }
        #pragma unroll
        for (int mt = 0; mt < 2; ++mt)
            #pragma unroll
            for (int nt = 0; nt < 4; ++nt)
                acc[mt][nt] = __builtin_amdgcn_mfma_f32_16x16x32_bf16(
                    fa[mt], fb[nt], acc[mt][nt], 0, 0, 0);
        if (step < 7) {
            #pragma unroll
            for (int mt = 0; mt < 2; ++mt) fa[mt] = na[mt];
            #pragma unroll
            for (int nt = 0; nt < 4; ++nt) fb[nt] = nb[nt];
        }
    }

    // Scatter: C/D layout col = lane&15, row = (lane>>4)*4 + reg (verified).
    int hr[2][4]; float sr[2][4]; int hc[4]; float sc[4];
    #pragma unroll
    for (int mt = 0; mt < 2; ++mt)
        #pragma unroll
        for (int rg = 0; rg < 4; ++rg) {
            int c1 = i0 + mt * 16 + (l >> 4) * 4 + rg;
            hr[mt][rg] = h[c1]; sr[mt][rg] = s[c1];
        }
    #pragma unroll
    for (int nt = 0; nt < 4; ++nt) {
        int c2 = j0 + nt * 16 + (l & 15);
        hc[nt] = h[C_DIM + c2]; sc[nt] = s[C_DIM + c2];
    }
    #pragma unroll
    for (int mt = 0; mt < 2; ++mt)
        #pragma unroll
        for (int nt = 0; nt < 4; ++nt)
            #pragma unroll
            for (int rg = 0; rg < 4; ++rg) {
                int bin = hr[mt][rg] + hc[nt];
                if (bin >= D_DIM) bin -= D_DIM;
                atomicAdd(&hist[bin], sr[mt][rg] * sc[nt] * acc[mt][nt][rg]);
            }
    __syncthreads();

    // Flush: plain coalesced float4 stores to this block's partial slice.
    const int slot = b * 16 + ib * 4 + jb;
    float* pb = part + (size_t)slot * D_DIM;
    #pragma unroll
    for (int l4 = 0; l4 < 4; ++l4) {
        int i4 = l4 * 512 + tid;
        if (i4 < D_DIM / 4)
            ((float4*)pb)[i4] = ((const float4*)hist)[i4];
    }
}

// ---------------------------------------------------------------------------
// Kernel 3: reduce the 16 partials of each batch -> out[b, d].
// Regrid R3: 250 blocks x 128 = exactly B*D/4 = 32000 items (no tail check),
// ~2x the CU coverage of the old 125x256 grid. float4 loads, plain stores;
// fully overwrites out (no memset needed).
// ---------------------------------------------------------------------------
__global__ __launch_bounds__(128) void reduce_part(
    const float* __restrict__ part, float* __restrict__ out) {
    int i4 = blockIdx.x * 128 + threadIdx.x;     // over B*D/4 = 32000 exactly
    int b = i4 / (D_DIM / 4);
    int d = i4 - b * (D_DIM / 4);
    const float4* p = (const float4*)(part + (size_t)b * 16 * D_DIM) + d;
    float4 v = {0.f, 0.f, 0.f, 0.f};
    #pragma unroll
    for (int t = 0; t < 16; ++t) {
        float4 q = p[(size_t)t * (D_DIM / 4)];
        v.x += q.x; v.y += q.y; v.z += q.z; v.w += q.w;
    }
    ((float4*)out)[i4] = v;
}

extern "C" void kernel_launch(void* const* d_in, const int* in_sizes, int n_in,
                              void* d_out, int out_size, void* d_ws, size_t ws_size,
                              hipStream_t stream) {
    const float* x  = (const float*)d_in[0];  // [16, 512, 14, 14] fp32
    const float* S1 = (const float*)d_in[1];  // [512, 8000] fp32
    const float* S2 = (const float*)d_in[2];  // [512, 8000] fp32
    float* out = (float*)d_out;               // [16, 8000] fp32

    // ws: h[1024] int | s[1024] f32 | xp[8192*224] bf16 (3.7 MB)
    //   | part[256*8000] f32 (8.2 MB)
    int*            h    = (int*)d_ws;
    float*          s    = (float*)(h + 2 * C_DIM);
    unsigned short* xp   = (unsigned short*)(s + 2 * C_DIM);
    float*          part = (float*)(xp + (size_t)NROW * KP);

    prep<<<1024, 256, 0, stream>>>(x, S1, S2, h, s, xp);

    dim3 grid(4, 4, B_DIM);                   // 256 blocks, 128x128 tiles
    gram_hist<<<grid, 512, 0, stream>>>(xp, h, s, part);

    reduce_part<<<(B_DIM * D_DIM / 4) / 128, 128, 0, stream>>>(part, out);
}